// Round 7
// baseline (138.196 us; speedup 1.0000x reference)
//
#include <hip/hip_runtime.h>

#define RES   64
#define RES2  4096
#define RES3  262144
#define CIN   16
#define COUT  32

// Padded fp16 tensor in ws: [b][z1:66][y1:66][hi:2][s:68][c8:8] halfs.
// z1=z+1, y1=y+1, s=x+1; out-of-range positions stored as 0 -> conv staging
// has NO bounds checks.
#define PZ 66
#define PY 66
#define ROWB  1088                    // bytes of one (hi) row: 68*16
#define PROWB 2176                    // bytes per (b,z1,y1)
#define XH16_BYTES (2*PZ*PY*PROWB)    // 18,957,312
#define NCHUNK (XH16_BYTES/16)        // 1,184,832 uint4 chunks
#define WTG_OFF ((XH16_BYTES + 255) & ~255)
#define NWH (27*CIN*COUT)             // 13824 weight halfs, [tap][hi][o][c8]

// conv tile: 2(z) x 4(y) x 64(x), 512 threads (8 waves), 2 ctiles/wave.
// LDS holds ONLY the x tile (weights are read from global / L1):
// 52224 B -> 3 resident blocks/CU.
#define TZ 2
#define TY 4
#define XT_BYTES (4*6*PROWB)          // 48 rows * 1088 = 52224
#define LDS_BYTES XT_BYTES

typedef _Float16 f16x8 __attribute__((ext_vector_type(8)));
typedef float   f32x16 __attribute__((ext_vector_type(16)));

static __device__ __forceinline__ unsigned int pack2(float v0, float v1) {
    _Float16 h0 = (_Float16)v0;
    _Float16 h1 = (_Float16)v1;
    unsigned short u0 = __builtin_bit_cast(unsigned short, h0);
    unsigned short u1 = __builtin_bit_cast(unsigned short, h1);
    return (unsigned int)u0 | ((unsigned int)u1 << 16);
}

typedef __attribute__((address_space(1))) const unsigned int gu32;
typedef __attribute__((address_space(3))) unsigned int lu32;
static __device__ __forceinline__ void glds16(const void* g, void* l) {
    __builtin_amdgcn_global_load_lds((gu32*)g, (lu32*)l, 16, 0, 0);
}

// ---- Kernel 1: x fp32 -> padded fp16 tensor; block 0 also converts W ------
__global__ __launch_bounds__(256) void xcvt_kernel(
    const float* __restrict__ x, uint4* __restrict__ xh16,
    const float* __restrict__ w, _Float16* __restrict__ wtg) {

    if (blockIdx.x == 0) {
        // weights fp32 [o][ci][27] -> fp16 [tap][hi][o][c8]
        for (int i = threadIdx.x; i < NWH; i += 256) {
            int tap = i >> 9;
            int hi  = (i >> 8) & 1;
            int o   = (i >> 3) & 31;
            int c   = i & 7;
            int ci  = hi * 8 + c;
            wtg[i] = (_Float16)w[(o * CIN + ci) * 27 + tap];
        }
    }

    for (int idx = blockIdx.x * 256 + threadIdx.x; idx < NCHUNK;
         idx += 2048 * 256) {
        int row = idx / 136;          // (b,z1,y1)
        int rem = idx - row * 136;
        int hi  = rem / 68;
        int s   = rem - hi * 68;
        int y1  = row % 66;
        int t   = row / 66;
        int z1  = t % 66;
        int b   = t / 66;

        uint4 val = make_uint4(0u, 0u, 0u, 0u);
        if (z1 >= 1 && z1 <= 64 && y1 >= 1 && y1 <= 64 && s >= 1 && s <= 64) {
            const float* sp = x + ((size_t)(b * CIN + hi * 8)) * RES3
                                + (z1 - 1) * RES2 + (y1 - 1) * RES + (s - 1);
            float f0 = sp[0 * RES3], f1 = sp[1 * RES3];
            float f2 = sp[2 * RES3], f3 = sp[3 * RES3];
            float f4 = sp[4 * RES3], f5 = sp[5 * RES3];
            float f6 = sp[6 * RES3], f7 = sp[7 * RES3];
            val.x = pack2(f0, f1);
            val.y = pack2(f2, f3);
            val.z = pack2(f4, f5);
            val.w = pack2(f6, f7);
        }
        xh16[idx] = val;
    }
}

// ---- Kernel 2: MFMA conv; x tile in LDS, weights direct from L1 ----------
__global__ __launch_bounds__(512, 6) void conv_kernel(
    const char* __restrict__ xh16b, const char* __restrict__ wtgb,
    float* __restrict__ out) {

    extern __shared__ char smem[];
    char* xt = smem;                  // [R:48][68][16B]  R=(iz*6+iy)*2+hi

    // 1024 blocks, bijective XCD swizzle
    int bid = blockIdx.x;
    int sb  = (bid & 7) * 128 + (bid >> 3);
    int b   = sb >> 9;
    int zt  = (sb >> 4) & 31;
    int yt  = sb & 15;
    int z0 = zt * TZ, y0 = yt * TY;

    int tid  = threadIdx.x;
    int lane = tid & 63;
    int wv   = tid >> 6;              // 0..7
    int hi   = lane >> 5;
    int l31  = lane & 31;

    // ---- stage x tile: 48 rows of 1088 B via global_load_lds, no bounds ----
    #pragma unroll
    for (int j = 0; j < 6; ++j) {
        int R   = wv * 6 + j;         // 0..47
        int iz  = R / 12;
        int rm  = R - iz * 12;
        int iy  = rm >> 1;
        int hh  = rm & 1;
        const char* srow = xh16b +
            ((((size_t)b * PZ + (z0 + iz)) * PY + (y0 + iy)) * 2 + hh) * (size_t)ROWB;
        char* drow = xt + R * ROWB;
        glds16(srow + lane * 16, drow);
        if (lane < 4) glds16(srow + 1024 + lane * 16, drow + 1024);
    }
    __syncthreads();

    // ---- wave -> 2 column tiles: (oz=0, acc0) and (oz=1, acc1) ----
    int oy = (wv >> 1) & 3;
    int xh = wv & 1;

    const int b_lane = hi * ROWB + (xh * 32 + 1 + l31) * 16;
    const int a_lane = hi * 512 + l31 * 16;
    const char* wlane = wtgb + a_lane;

    f32x16 acc0 = {};
    f32x16 acc1 = {};

    __builtin_amdgcn_s_setprio(1);
    #pragma unroll
    for (int tap = 0; tap < 27; ++tap) {
        const int dz  = tap / 9 - 1;
        const int dy  = (tap / 3) % 3 - 1;
        const int dxx = tap % 3 - 1;
        // acc0 rows: iz = 1+dz; acc1: iz = 2+dz (delta = 12 rows)
        const int u0 = (((1 + dz) * 6 + (oy + 1 + dy)) * 2) * ROWB + dxx * 16;
        f16x8 af = *(const f16x8*)(wlane + tap * 1024);   // global, L1-hot
        f16x8 b0 = *(const f16x8*)(xt + u0 + b_lane);
        f16x8 b1 = *(const f16x8*)(xt + u0 + 12 * ROWB + b_lane);
        acc0 = __builtin_amdgcn_mfma_f32_32x32x16_f16(af, b0, acc0, 0, 0, 0);
        acc1 = __builtin_amdgcn_mfma_f32_32x32x16_f16(af, b1, acc1, 0, 0, 0);
    }
    __builtin_amdgcn_s_setprio(0);

    // ---- epilogue: occupancy from staged fp16 (&0x7FFF kills -0.0) ----
    const int ixb = (xh * 32 + 1 + l31) * 16;
    #pragma unroll
    for (int oz = 0; oz < 2; ++oz) {
        int R = (((oz + 1) * 6) + (oy + 1)) * 2;
        const uint4 a = *(const uint4*)(xt + R * ROWB + ixb);
        const uint4 c = *(const uint4*)(xt + (R + 1) * ROWB + ixb);
        unsigned m = (a.x | a.y | a.z | a.w | c.x | c.y | c.z | c.w) & 0x7FFF7FFFu;
        bool occ = (m != 0u);
        size_t vaddr = (size_t)(z0 + oz) * RES2 + (y0 + oy) * RES + xh * 32 + l31;
        const f32x16& acc = oz ? acc1 : acc0;
        #pragma unroll
        for (int r = 0; r < 16; ++r) {
            int o = (r & 3) + 8 * (r >> 2) + 4 * hi;
            float val = occ ? acc[r] : 0.0f;
            out[((size_t)(b * COUT + o) << 18) + vaddr] = val;
        }
    }
}

extern "C" void kernel_launch(void* const* d_in, const int* in_sizes, int n_in,
                              void* d_out, int out_size, void* d_ws, size_t ws_size,
                              hipStream_t stream) {
    const float* x = (const float*)d_in[0];   // [2,16,64,64,64]
    const float* w = (const float*)d_in[1];   // [1,32,16,3,3,3]
    float* out = (float*)d_out;               // [2,32,64,64,64]

    uint4*    xh16 = (uint4*)d_ws;                       // 18.96 MB
    _Float16* wtg  = (_Float16*)((char*)d_ws + WTG_OFF); // 27648 B

    (void)hipFuncSetAttribute(reinterpret_cast<const void*>(conv_kernel),
                              hipFuncAttributeMaxDynamicSharedMemorySize, LDS_BYTES);

    xcvt_kernel<<<2048, 256, 0, stream>>>(x, xh16, w, wtg);
    conv_kernel<<<1024, 512, LDS_BYTES, stream>>>((const char*)xh16,
                                                  (const char*)wtg, out);
}

// Round 8
// 120.056 us; speedup vs baseline: 1.1511x; 1.1511x over previous
//
#include <hip/hip_runtime.h>

#define RES   64
#define RES2  4096
#define RES3  262144
#define CIN   16
#define COUT  32

// Padded fp16 tensor in ws: [b][z1:66][y1:66][hi:2][s:68][c8:8] halfs.
// z1=z+1, y1=y+1, s=x+1; out-of-range positions stored as 0.
#define PZ 66
#define PY 66
#define ROWB  1088                    // bytes of one (hi) row: 68*16
#define XH16_BYTES (2*PZ*PY*2*ROWB)   // 18,957,312
#define NCHUNK (XH16_BYTES/16)
#define WTG_OFF ((XH16_BYTES + 255) & ~255)
#define NWH (27*CIN*COUT)             // 13824 weight halfs, [tap][hi][o][c8]

// conv tile: 4(z) x 4(y) x 64(x), 512 threads (8 waves).
// LDS: x tile only: 6 z-slabs * 6 y * 2 hi = 72 rows * 1088 B = 78336
// -> 2 resident blocks/CU. Weights read from global (L1-hot) in 3-frag batches.
#define XT_BYTES (72*ROWB)
#define LDS_BYTES XT_BYTES

typedef _Float16 f16x8 __attribute__((ext_vector_type(8)));
typedef float   f32x16 __attribute__((ext_vector_type(16)));

static __device__ __forceinline__ unsigned int pack2(float v0, float v1) {
    _Float16 h0 = (_Float16)v0;
    _Float16 h1 = (_Float16)v1;
    unsigned short u0 = __builtin_bit_cast(unsigned short, h0);
    unsigned short u1 = __builtin_bit_cast(unsigned short, h1);
    return (unsigned int)u0 | ((unsigned int)u1 << 16);
}

typedef __attribute__((address_space(1))) const unsigned int gu32;
typedef __attribute__((address_space(3))) unsigned int lu32;
static __device__ __forceinline__ void glds16(const void* g, void* l) {
    __builtin_amdgcn_global_load_lds((gu32*)g, (lu32*)l, 16, 0, 0);
}

// ---- Kernel 1: x fp32 -> padded fp16; block 0 also converts weights ------
__global__ __launch_bounds__(256) void xcvt_kernel(
    const float* __restrict__ x, uint4* __restrict__ xh16,
    const float* __restrict__ w, _Float16* __restrict__ wtg) {

    if (blockIdx.x == 0) {
        for (int i = threadIdx.x; i < NWH; i += 256) {
            int tap = i >> 9;
            int hi  = (i >> 8) & 1;
            int o   = (i >> 3) & 31;
            int c   = i & 7;
            int ci  = hi * 8 + c;
            wtg[i] = (_Float16)w[(o * CIN + ci) * 27 + tap];
        }
    }

    for (int idx = blockIdx.x * 256 + threadIdx.x; idx < NCHUNK;
         idx += 2048 * 256) {
        int row = idx / 136;          // (b,z1,y1)
        int rem = idx - row * 136;
        int hi  = rem / 68;
        int s   = rem - hi * 68;
        int y1  = row % 66;
        int t   = row / 66;
        int z1  = t % 66;
        int b   = t / 66;

        uint4 val = make_uint4(0u, 0u, 0u, 0u);
        if (z1 >= 1 && z1 <= 64 && y1 >= 1 && y1 <= 64 && s >= 1 && s <= 64) {
            const float* sp = x + ((size_t)(b * CIN + hi * 8)) * RES3
                                + (z1 - 1) * RES2 + (y1 - 1) * RES + (s - 1);
            val.x = pack2(sp[0 * RES3], sp[1 * RES3]);
            val.y = pack2(sp[2 * RES3], sp[3 * RES3]);
            val.z = pack2(sp[4 * RES3], sp[5 * RES3]);
            val.w = pack2(sp[6 * RES3], sp[7 * RES3]);
        }
        xh16[idx] = val;
    }
}

// ---- Kernel 2: MFMA conv, 4x4x64 tile; full-line stores ------------------
__global__ __launch_bounds__(512, 4) void conv_kernel(
    const char* __restrict__ xh16b, const char* __restrict__ wtgb,
    float* __restrict__ out) {

    extern __shared__ char smem[];
    char* xt = smem;                  // [R:72][68][16B]  R=(iz*6+iy)*2+hi

    // 512 blocks, bijective XCD swizzle (512 % 8 == 0)
    int bid = blockIdx.x;
    int sb  = (bid & 7) * 64 + (bid >> 3);
    int b   = sb >> 8;                // batch
    int zt  = (sb >> 4) & 15;
    int yt  = sb & 15;
    int z0 = zt * 4, y0 = yt * 4;

    int tid  = threadIdx.x;
    int lane = tid & 63;
    int wv   = tid >> 6;              // 0..7
    int hi   = lane >> 5;
    int l31  = lane & 31;

    // ---- stage 72 rows of 1088 B via global_load_lds (no bounds checks) ----
    #pragma unroll
    for (int j = 0; j < 9; ++j) {
        int R   = wv * 9 + j;         // 0..71
        int iz  = R / 12;
        int rm  = R - iz * 12;
        int iy  = rm >> 1;
        int hh  = rm & 1;
        const char* srow = xh16b +
            ((((size_t)b * PZ + (z0 + iz)) * PY + (y0 + iy)) * 2 + hh) * (size_t)ROWB;
        char* drow = xt + R * ROWB;
        glds16(srow + lane * 16, drow);
        if (lane < 4) glds16(srow + 1024 + lane * 16, drow + 1024);
    }
    __syncthreads();

    // ---- wave -> (ozp, oy): two z rows (oz0, oz0+1), both x-halves --------
    int oy  = wv & 3;
    int oz0 = (wv >> 2) * 2;          // 0 or 2

    const int hb = hi * ROWB;
    const char* xbase = xt + hb + l31 * 16;       // + row*ROWB + xh*512 + dxp*16
    const char* wtab  = wtgb + hi * 512 + l31 * 16;

    f32x16 acc00 = {};   // (oz0,   xh0)
    f32x16 acc01 = {};   // (oz0,   xh1)
    f32x16 acc10 = {};   // (oz0+1, xh0)
    f32x16 acc11 = {};   // (oz0+1, xh1)

    #pragma unroll
    for (int g = 0; g < 3; ++g) {                 // dz = g-1
        #pragma unroll
        for (int dyp = 0; dyp < 3; ++dyp) {       // dy = dyp-1
            const char* wp = wtab + (size_t)(g * 9 + dyp * 3) * 1024;
            f16x8 wf0 = *(const f16x8*)(wp);
            f16x8 wf1 = *(const f16x8*)(wp + 1024);
            f16x8 wf2 = *(const f16x8*)(wp + 2048);
            // slab for acc0*: iz = oz0+g; acc1*: iz = oz0+g+1 (+12 rows)
            const char* xrow = xbase + (((oz0 + g) * 6 + (oy + dyp)) * 2) * ROWB;
            #pragma unroll
            for (int dxp = 0; dxp < 3; ++dxp) {
                f16x8 wf = (dxp == 0) ? wf0 : ((dxp == 1) ? wf1 : wf2);
                f16x8 bA0 = *(const f16x8*)(xrow + dxp * 16);
                f16x8 bA1 = *(const f16x8*)(xrow + 512 + dxp * 16);
                f16x8 bB0 = *(const f16x8*)(xrow + 12 * ROWB + dxp * 16);
                f16x8 bB1 = *(const f16x8*)(xrow + 12 * ROWB + 512 + dxp * 16);
                acc00 = __builtin_amdgcn_mfma_f32_32x32x16_f16(wf, bA0, acc00, 0, 0, 0);
                acc01 = __builtin_amdgcn_mfma_f32_32x32x16_f16(wf, bA1, acc01, 0, 0, 0);
                acc10 = __builtin_amdgcn_mfma_f32_32x32x16_f16(wf, bB0, acc10, 0, 0, 0);
                acc11 = __builtin_amdgcn_mfma_f32_32x32x16_f16(wf, bB1, acc11, 0, 0, 0);
            }
        }
    }

    // ---- epilogue: occupancy masks (&0x7FFF kills -0.0), full-line stores --
    // mask rows: iz = oz+1, iy = oy+1; col chunk = xh*32 + l31 + 1
    unsigned occm[2][2];
    #pragma unroll
    for (int ozo = 0; ozo < 2; ++ozo) {
        int R = (((oz0 + ozo + 1) * 6) + (oy + 1)) * 2;
        #pragma unroll
        for (int xh = 0; xh < 2; ++xh) {
            const char* mp = xt + R * ROWB + (xh * 32 + l31 + 1) * 16;
            uint4 a = *(const uint4*)(mp);
            uint4 c = *(const uint4*)(mp + ROWB);
            occm[ozo][xh] = (a.x | a.y | a.z | a.w | c.x | c.y | c.z | c.w) & 0x7FFF7FFFu;
        }
    }
    bool oA0 = occm[0][0] != 0u, oA1 = occm[0][1] != 0u;
    bool oB0 = occm[1][0] != 0u, oB1 = occm[1][1] != 0u;

    size_t vaddrA = (size_t)(z0 + oz0) * RES2 + (y0 + oy) * RES + l31;
    size_t vaddrB = vaddrA + RES2;

    #pragma unroll
    for (int r = 0; r < 16; ++r) {
        int o = (r & 3) + 8 * (r >> 2) + 4 * hi;
        float* pl = out + ((size_t)(b * COUT + o) << 18);
        // z row oz0: both halves back-to-back -> full 256B line from one wave
        pl[vaddrA]      = oA0 ? acc00[r] : 0.0f;
        pl[vaddrA + 32] = oA1 ? acc01[r] : 0.0f;
        // z row oz0+1
        pl[vaddrB]      = oB0 ? acc10[r] : 0.0f;
        pl[vaddrB + 32] = oB1 ? acc11[r] : 0.0f;
    }
}

extern "C" void kernel_launch(void* const* d_in, const int* in_sizes, int n_in,
                              void* d_out, int out_size, void* d_ws, size_t ws_size,
                              hipStream_t stream) {
    const float* x = (const float*)d_in[0];   // [2,16,64,64,64]
    const float* w = (const float*)d_in[1];   // [1,32,16,3,3,3]
    float* out = (float*)d_out;               // [2,32,64,64,64]

    uint4*    xh16 = (uint4*)d_ws;                       // 18.96 MB
    _Float16* wtg  = (_Float16*)((char*)d_ws + WTG_OFF); // 27648 B

    (void)hipFuncSetAttribute(reinterpret_cast<const void*>(conv_kernel),
                              hipFuncAttributeMaxDynamicSharedMemorySize, LDS_BYTES);

    xcvt_kernel<<<2048, 256, 0, stream>>>(x, xh16, w, wtg);
    conv_kernel<<<512, 512, LDS_BYTES, stream>>>((const char*)xh16,
                                                 (const char*)wtg, out);
}

// Round 10
// 101.901 us; speedup vs baseline: 1.3562x; 1.1782x over previous
//
#include <hip/hip_runtime.h>

#define RES   64
#define RES2  4096
#define RES3  262144
#define CIN   16
#define COUT  32
#define NWH (27*CIN*COUT)             // 13824 weight halfs, [tap][hi][o][c8]

// conv tile: 4(z) x 4(y) x 64(x), 512 threads (8 waves), fused fp32->fp16
// staging. LDS x tile: rows R=(iz*6+iy)*2+hi, 72 rows x 68 chunks x 16 B.
// Chunk c holds x-position gx=c-1; c in {0,65,66,67} is always zero (x pad).
#define ROWB  1088
#define XT_BYTES (72*ROWB)            // 78336 -> 2 resident blocks/CU
#define LDS_BYTES XT_BYTES

typedef _Float16 f16x8 __attribute__((ext_vector_type(8)));
typedef float   f32x16 __attribute__((ext_vector_type(16)));

static __device__ __forceinline__ unsigned int pack2(float v0, float v1) {
    _Float16 h0 = (_Float16)v0;
    _Float16 h1 = (_Float16)v1;
    unsigned short u0 = __builtin_bit_cast(unsigned short, h0);
    unsigned short u1 = __builtin_bit_cast(unsigned short, h1);
    return (unsigned int)u0 | ((unsigned int)u1 << 16);
}

// ---- Kernel 1: weights fp32 [o][ci][27] -> fp16 [tap][hi][o][c8] ---------
__global__ __launch_bounds__(256) void wtrans_kernel(
    const float* __restrict__ w, _Float16* __restrict__ wtg) {
    int i = blockIdx.x * 256 + threadIdx.x;
    if (i >= NWH) return;
    int tap = i >> 9;
    int hi  = (i >> 8) & 1;
    int o   = (i >> 3) & 31;
    int c   = i & 7;
    wtg[i] = (_Float16)w[(o * CIN + hi * 8 + c) * 27 + tap];
}

// ---- Kernel 2: fused stage(fp32->fp16) + MFMA conv + masked store --------
__global__ __launch_bounds__(512, 4) void conv_kernel(
    const float* __restrict__ x, const char* __restrict__ wtgb,
    float* __restrict__ out) {

    extern __shared__ char smem[];
    char* xt = smem;                  // [R:72][68][16B]

    // 512 blocks, bijective XCD swizzle (512 % 8 == 0)
    int bid = blockIdx.x;
    int sb  = (bid & 7) * 64 + (bid >> 3);
    int b   = sb >> 8;                // batch
    int zt  = (sb >> 4) & 15;
    int yt  = sb & 15;
    int z0 = zt * 4, y0 = yt * 4;

    int tid  = threadIdx.x;
    int lane = tid & 63;
    int wv   = tid >> 6;              // 0..7
    int hi   = lane >> 5;
    int l31  = lane & 31;

    // ---- fused staging: 36 (iz,iy) pairs, wave-strided ----
    const float* xb = x + (size_t)b * CIN * RES3;
    const uint4 zz = make_uint4(0u, 0u, 0u, 0u);
    #pragma unroll
    for (int j = 0; j < 5; ++j) {
        int p = wv + j * 8;
        if (p >= 36) break;                        // wave-uniform
        int iz = p / 6, iy = p - iz * 6;
        int gz = z0 + iz - 1, gy = y0 + iy - 1;
        char* d0 = xt + (p * 2) * ROWB;            // hi=0 row; hi=1 at +ROWB
        uint4 lo = zz, hh = zz;
        if (((unsigned)gz < 64u) && ((unsigned)gy < 64u)) {   // uniform branch
            const float* sp = xb + gz * RES2 + gy * RES + lane;   // gx = lane
            float v0  = sp[0];          float v1  = sp[RES3];
            float v2  = sp[2 * RES3];   float v3  = sp[3 * RES3];
            float v4  = sp[4 * RES3];   float v5  = sp[5 * RES3];
            float v6  = sp[6 * RES3];   float v7  = sp[7 * RES3];
            float v8  = sp[8 * RES3];   float v9  = sp[9 * RES3];
            float v10 = sp[10 * RES3];  float v11 = sp[11 * RES3];
            float v12 = sp[12 * RES3];  float v13 = sp[13 * RES3];
            float v14 = sp[14 * RES3];  float v15 = sp[15 * RES3];
            lo = make_uint4(pack2(v0, v1),  pack2(v2, v3),
                            pack2(v4, v5),  pack2(v6, v7));
            hh = make_uint4(pack2(v8, v9),  pack2(v10, v11),
                            pack2(v12, v13), pack2(v14, v15));
        }
        *(uint4*)(d0 + (lane + 1) * 16)        = lo;   // chunk c = gx+1
        *(uint4*)(d0 + ROWB + (lane + 1) * 16) = hh;
        if (lane < 4) {                         // boundary chunks 0,65,66,67
            int cz = (lane == 0) ? 0 : (64 + lane);
            *(uint4*)(d0 + cz * 16)        = zz;
            *(uint4*)(d0 + ROWB + cz * 16) = zz;
        }
    }
    __syncthreads();

    // ---- wave -> (oz pair, oy): rows oz0, oz0+1; both x-halves ----
    int oy  = wv & 3;
    int oz0 = (wv >> 2) * 2;          // 0 or 2

    const char* xbase = xt + hi * ROWB + l31 * 16;
    const char* wtab  = wtgb + hi * 512 + l31 * 16;

    f32x16 acc00 = {};   // (oz0,   xh0)
    f32x16 acc01 = {};   // (oz0,   xh1)
    f32x16 acc10 = {};   // (oz0+1, xh0)
    f32x16 acc11 = {};   // (oz0+1, xh1)

    #pragma unroll
    for (int g = 0; g < 3; ++g) {                 // dz = g-1
        #pragma unroll
        for (int dyp = 0; dyp < 3; ++dyp) {       // dy = dyp-1
            const char* wp = wtab + (size_t)(g * 9 + dyp * 3) * 1024;
            f16x8 wf0 = *(const f16x8*)(wp);
            f16x8 wf1 = *(const f16x8*)(wp + 1024);
            f16x8 wf2 = *(const f16x8*)(wp + 2048);
            const char* xrow = xbase + (((oz0 + g) * 6 + (oy + dyp)) * 2) * ROWB;
            #pragma unroll
            for (int dxp = 0; dxp < 3; ++dxp) {
                f16x8 wf = (dxp == 0) ? wf0 : ((dxp == 1) ? wf1 : wf2);
                f16x8 bA0 = *(const f16x8*)(xrow + dxp * 16);
                f16x8 bA1 = *(const f16x8*)(xrow + 512 + dxp * 16);
                f16x8 bB0 = *(const f16x8*)(xrow + 12 * ROWB + dxp * 16);
                f16x8 bB1 = *(const f16x8*)(xrow + 12 * ROWB + 512 + dxp * 16);
                acc00 = __builtin_amdgcn_mfma_f32_32x32x16_f16(wf, bA0, acc00, 0, 0, 0);
                acc01 = __builtin_amdgcn_mfma_f32_32x32x16_f16(wf, bA1, acc01, 0, 0, 0);
                acc10 = __builtin_amdgcn_mfma_f32_32x32x16_f16(wf, bB0, acc10, 0, 0, 0);
                acc11 = __builtin_amdgcn_mfma_f32_32x32x16_f16(wf, bB1, acc11, 0, 0, 0);
            }
        }
    }

    // ---- epilogue: occupancy masks (&0x7FFF kills -0.0), full-line stores --
    unsigned occm[2][2];
    #pragma unroll
    for (int ozo = 0; ozo < 2; ++ozo) {
        int R = (((oz0 + ozo + 1) * 6) + (oy + 1)) * 2;
        #pragma unroll
        for (int xh = 0; xh < 2; ++xh) {
            const char* mp = xt + R * ROWB + (xh * 32 + l31 + 1) * 16;
            uint4 a = *(const uint4*)(mp);
            uint4 c = *(const uint4*)(mp + ROWB);
            occm[ozo][xh] = (a.x | a.y | a.z | a.w | c.x | c.y | c.z | c.w) & 0x7FFF7FFFu;
        }
    }
    bool oA0 = occm[0][0] != 0u, oA1 = occm[0][1] != 0u;
    bool oB0 = occm[1][0] != 0u, oB1 = occm[1][1] != 0u;

    size_t vaddrA = (size_t)(z0 + oz0) * RES2 + (y0 + oy) * RES + l31;
    size_t vaddrB = vaddrA + RES2;

    #pragma unroll
    for (int r = 0; r < 16; ++r) {
        int o = (r & 3) + 8 * (r >> 2) + 4 * hi;
        float* pl = out + ((size_t)(b * COUT + o) << 18);
        pl[vaddrA]      = oA0 ? acc00[r] : 0.0f;
        pl[vaddrA + 32] = oA1 ? acc01[r] : 0.0f;
        pl[vaddrB]      = oB0 ? acc10[r] : 0.0f;
        pl[vaddrB + 32] = oB1 ? acc11[r] : 0.0f;
    }
}

extern "C" void kernel_launch(void* const* d_in, const int* in_sizes, int n_in,
                              void* d_out, int out_size, void* d_ws, size_t ws_size,
                              hipStream_t stream) {
    const float* x = (const float*)d_in[0];   // [2,16,64,64,64]
    const float* w = (const float*)d_in[1];   // [1,32,16,3,3,3]
    float* out = (float*)d_out;               // [2,32,64,64,64]

    _Float16* wtg = (_Float16*)d_ws;          // 27648 B

    (void)hipFuncSetAttribute(reinterpret_cast<const void*>(conv_kernel),
                              hipFuncAttributeMaxDynamicSharedMemorySize, LDS_BYTES);

    wtrans_kernel<<<(NWH + 255) / 256, 256, 0, stream>>>(w, wtg);
    conv_kernel<<<512, 512, LDS_BYTES, stream>>>(x, (const char*)wtg, out);
}